// Round 6
// baseline (285.342 us; speedup 1.0000x reference)
//
#include <hip/hip_runtime.h>
#include <stdint.h>

// Cost volume = 48-wide band of Gram matrix L^T R per (b,h), K = c = 128.
// bf16 MFMA 32x32x16.
// R10: fat-instruction streaming. R4-R9 (3 disjoint structures) all pin at
//   ~104us with every pipe <20% busy => latency-bound with ~30 outstanding
//   load instrs/CU. Common factor: thin 256B global_load_dword fragment
//   loads (7680/CU in R9). This round: ALL staging via global_load_lds
//   size16 (1 KB/instr, 8 fat DMA per 16-ch chunk vs 32 thin loads),
//   2-deep chunk pipeline (16 KB outstanding/wave, counted vmcnt(8),
//   never drained mid-loop), 1-wave blocks (no barriers, 16 KB LDS,
//   10 independent waves/CU). B staged once as a 96-col span serving all
//   3 disparity tiles. Pack f32->bf16 on LDS read (identical numerics).

typedef __bf16 bf16x8 __attribute__((ext_vector_type(8)));
typedef float floatx16 __attribute__((ext_vector_type(16)));

constexpr int W = 320, H = 96, C = 128, NB = 8, MAXD = 48;
constexpr int HW = H * W;          // 30720
constexpr int CH = 16;             // channels per chunk
constexpr int NCH = C / CH;        // 8 chunks
constexpr int TPP = W / 32;        // x-tiles per plane = 10
constexpr int NTASK = NB * H * TPP;  // 7680 wave-tasks
constexpr int ABD = CH * 32;       // A chunk dwords = 512  (2 KB)
constexpr int BBD = CH * 96;       // B chunk dwords = 1536 (6 KB)
constexpr int ESZ = MAXD * 33;     // epilogue scratch dwords = 1584

__device__ __forceinline__ uint32_t pack_bf16x2(float a, float b) {
    // RNE f32->bf16; (c even -> low16, c odd -> high16) == MFMA k-order.
    uint32_t ua = __float_as_uint(a), ub = __float_as_uint(b);
    uint32_t lo = (ua + 0x7fffu + ((ua >> 16) & 1u)) >> 16;
    uint32_t hi = (ub + 0x7fffu + ((ub >> 16) & 1u)) & 0xffff0000u;
    return hi | lo;
}

__device__ __forceinline__ bf16x8 packf(const float* v) {
    uint4 q;
    q.x = pack_bf16x2(v[0], v[1]);
    q.y = pack_bf16x2(v[2], v[3]);
    q.z = pack_bf16x2(v[4], v[5]);
    q.w = pack_bf16x2(v[6], v[7]);
    return __builtin_bit_cast(bf16x8, q);
}

// Direct global->LDS DMA: LDS dest = wave-uniform base + lane*16;
// global source address is per-lane.
#define GLDS16(gp, lp)                                                     \
    __builtin_amdgcn_global_load_lds(                                      \
        (const __attribute__((address_space(1))) void*)(gp),               \
        (__attribute__((address_space(3))) void*)(lp), 16, 0, 0)

__global__ __launch_bounds__(64) void cost_volume_kernel(
    const float* __restrict__ Lg, const float* __restrict__ Rg,
    float* __restrict__ out)
{
    // 16 KB: A dbuf (2x2 KB) + B dbuf (2x6 KB); reused as epilogue scratch
    // (1584 dw <= 4096). 10 blocks/CU by LDS.
    __shared__ uint32_t lds[2 * ABD + 2 * BBD];

    const int lane = threadIdx.x & 63;
    const int n    = lane & 31;
    const int half = lane >> 5;

    const int wid   = blockIdx.x;             // wave-task id
    const int plane = wid / TPP;
    const int p     = wid % TPP;              // x-tile (x0 = 32p)
    const int b     = plane / H;
    const int h     = plane % H;

    const int baseLR = b * (C * HW) + h * W;
    const int pcl    = (p < 2) ? p : 2;       // clamp for B-span indexing
    const int s0     = 32 * (p - pcl);        // B span start col (>=0, +96<=320)

    // ---- DMA source addressing (precomputed, chunk adds 16*cc*HW) ----
    // A instr i (i=0,1): lane l -> ch = i*8 + l/8, col-quad = l%8.
    const float* gA = Lg + baseLR + (lane >> 3) * HW + 32 * p + (lane & 7) * 4;
    // B instr i (i=0..5): flat quad Q = i*64+l -> ch = Q/24, quad = Q%24.
    // LDS linear dest dword 4Q == ch*96 + quad*4  => [ch][96col] layout.
    const float* gB[6];
#pragma unroll
    for (int i = 0; i < 6; ++i) {
        int Q = i * 64 + lane;
        gB[i] = Rg + baseLR + (Q / 24) * HW + s0 + (Q % 24) * 4;
    }

    auto dmaChunk = [&](int cc) {   // 8 fat DMA instrs, 8 KB
        const int go = CH * cc * HW;
        uint32_t* dA = lds + (cc & 1) * ABD;
        GLDS16(gA + go, dA);
        GLDS16(gA + go + 8 * HW, dA + 256);
        uint32_t* dB = lds + 2 * ABD + (cc & 1) * BBD;
#pragma unroll
        for (int i = 0; i < 6; ++i) GLDS16(gB[i] + go, dB + i * 256);
    };

    floatx16 acc0 = 0.f, acc1 = 0.f, acc2 = 0.f;  // q = p, p-1, p-2

    dmaChunk(0);
    dmaChunk(1);

#pragma unroll
    for (int cc = 0; cc < NCH; ++cc) {
        // Drain exactly chunk cc's 8 DMAs; chunk cc+1's 8 stay in flight.
        if (cc + 1 < NCH)
            asm volatile("s_waitcnt vmcnt(8)" ::: "memory");
        else
            asm volatile("s_waitcnt vmcnt(0)" ::: "memory");

        // ---- fragment reads (f32) from this chunk's buffers ----
        const float* Af = reinterpret_cast<const float*>(lds + (cc & 1) * ABD)
                        + 8 * half * 32 + n;
        const float* Bb = reinterpret_cast<const float*>(lds + 2 * ABD + (cc & 1) * BBD)
                        + 8 * half * 96 + n;
        float av[8], b0v[8], b1v[8], b2v[8];
#pragma unroll
        for (int k = 0; k < 8; ++k) av[k] = Af[k * 32];
        {
            const float* Bf = Bb + 32 * pcl;          // q = p
#pragma unroll
            for (int k = 0; k < 8; ++k) b0v[k] = Bf[k * 96];
        }
        if (p >= 1) {
            const float* Bf = Bb + 32 * (pcl - 1);    // q = p-1
#pragma unroll
            for (int k = 0; k < 8; ++k) b1v[k] = Bf[k * 96];
        }
        if (p >= 2) {
            const float* Bf = Bb + 32 * (pcl - 2);    // q = p-2
#pragma unroll
            for (int k = 0; k < 8; ++k) b2v[k] = Bf[k * 96];
        }

        // All ds_reads of this buffer must COMPLETE before DMA(cc+2)
        // overwrites it (rule #18: lgkmcnt asm + sched_barrier fence).
        asm volatile("s_waitcnt lgkmcnt(0)" ::: "memory");
        __builtin_amdgcn_sched_barrier(0);
        if (cc + 2 < NCH) dmaChunk(cc + 2);
        // -> steady state: 16 KB (2 chunks) of DMA in flight across the
        //    packs + MFMAs below and the next iteration's wait.

        bf16x8 af = packf(av);
        acc0 = __builtin_amdgcn_mfma_f32_32x32x16_bf16(
            af, packf(b0v), acc0, 0, 0, 0);
        if (p >= 1)
            acc1 = __builtin_amdgcn_mfma_f32_32x32x16_bf16(
                af, packf(b1v), acc1, 0, 0, 0);
        if (p >= 2)
            acc2 = __builtin_amdgcn_mfma_f32_32x32x16_bf16(
                af, packf(b2v), acc2, 0, 0, 0);
    }

    // ---- epilogue: band -> wave-private LDS transpose -> coalesced stores
    // D layout (verified): x = 32p + m, m = (r&3) + 8*(r>>2) + 4*half,
    // i = 32*DP + m - n. Single wave per block: no barriers needed.
    asm volatile("s_waitcnt lgkmcnt(0)" ::: "memory");  // staging reads done
    float* sS = reinterpret_cast<float*>(lds);
    const int ob = b * (MAXD * HW) + h * W + p * 32;
    constexpr float scale = 1.f / 128.f;

    if (p < 2) {  // only x<64 has an i>x zero triangle
        for (int e = lane; e < ESZ; e += 64) sS[e] = 0.f;
    }

#define FILL_TILE(DP, ACC)                                                  \
    if (p >= (DP)) {                                                        \
        _Pragma("unroll")                                                   \
        for (int r = 0; r < 16; ++r) {                                      \
            int m = (r & 3) + 8 * (r >> 2) + 4 * half;                      \
            int i = 32 * (DP) + m - n;                                      \
            if (i >= 0 && i < MAXD)                                         \
                sS[i * 33 + m] = ACC[r] * scale;                            \
        }                                                                   \
    }
    FILL_TILE(0, acc0)
    FILL_TILE(1, acc1)
    FILL_TILE(2, acc2)
#undef FILL_TILE

#pragma unroll
    for (int e = 0; e < 24; ++e) {
        int idx = e * 64 + lane;
        int i = idx >> 5;        // disparity 0..47
        int m = idx & 31;        // x-local
        out[ob + i * HW + m] = sS[i * 33 + m];
    }
}

extern "C" void kernel_launch(void* const* d_in, const int* in_sizes, int n_in,
                              void* d_out, int out_size, void* d_ws, size_t ws_size,
                              hipStream_t stream) {
    const float* L = (const float*)d_in[0];
    const float* R = (const float*)d_in[1];
    float* out = (float*)d_out;
    cost_volume_kernel<<<dim3(NTASK), dim3(64), 0, stream>>>(L, R, out);
}